// Round 1
// 603.698 us; speedup vs baseline: 1.2845x; 1.2845x over previous
//
#include <hip/hip_runtime.h>
#include <cstdint>
#include <cstddef>

static constexpr int NN = 100000;   // nodes
static constexpr int NE = 1600000;  // edges
static constexpr int NP = 100096;   // NN padded to 128-row GEMM granularity

static constexpr int NBUCK = 391;   // ceil(NN / 256) node buckets (bucket = node >> 8)
static constexpr int BCAP  = 5120;  // bucket capacity: mean 4096 + 16 sigma
static constexpr int PBLK  = 200;   // partition blocks
static constexpr int EPB   = 8000;  // edges per partition block (PBLK*EPB == NE)

typedef __attribute__((ext_vector_type(8))) short short8;             // 8 bf16 (4 VGPRs)
typedef __attribute__((ext_vector_type(8))) unsigned short ushort8;   // 16B bf16 chunk
typedef __attribute__((ext_vector_type(4))) float f32x4;              // MFMA C/D frag

__device__ inline ushort bf16_rtn(float x) {
    uint32_t u = __float_as_uint(x);
    uint32_t r = u + 0x7fffu + ((u >> 16) & 1u);   // round-to-nearest-even
    return (ushort)(r >> 16);
}
__device__ inline float bf16_to_f(ushort u) {
    return __uint_as_float((uint32_t)u << 16);
}

// ---------------- bucket cursors init ----------------
__global__ __launch_bounds__(256) void k_init_cur(int* __restrict__ cur_d, int* __restrict__ cur_s) {
    int b = blockIdx.x * 256 + threadIdx.x;
    if (b < NBUCK) { cur_d[b] = b * BCAP; cur_s[b] = b * BCAP; }
}

// ---------------- two-level partition: edges -> dst buckets (packed pair) + src buckets (byte) ----
// LDS histogram per block -> one global atomic per (block,bucket) -> chunked writes.
// Replaces 3.2M scattered global atomics with ~156K.
__global__ __launch_bounds__(256) void k_partition(const int* __restrict__ src, const int* __restrict__ dst,
                                                   int* __restrict__ cur_d, int* __restrict__ cur_s,
                                                   int* __restrict__ pairs, unsigned char* __restrict__ bsrc) {
    __shared__ int hd[NBUCK];
    __shared__ int hs[NBUCK];
    int e0 = blockIdx.x * EPB;
    for (int i = threadIdx.x; i < NBUCK; i += 256) { hd[i] = 0; hs[i] = 0; }
    __syncthreads();
    for (int e = e0 + (int)threadIdx.x; e < e0 + EPB; e += 256) {
        atomicAdd(&hd[dst[e] >> 8], 1);
        atomicAdd(&hs[src[e] >> 8], 1);
    }
    __syncthreads();
    for (int i = threadIdx.x; i < NBUCK; i += 256) {
        int c = hd[i];
        hd[i] = c ? atomicAdd(&cur_d[i], c) : 0;   // becomes this block's write cursor
        c = hs[i];
        hs[i] = c ? atomicAdd(&cur_s[i], c) : 0;
    }
    __syncthreads();
    for (int e = e0 + (int)threadIdx.x; e < e0 + EPB; e += 256) {
        int s = src[e], d = dst[e];
        int p = atomicAdd(&hd[d >> 8], 1);
        pairs[p] = (s << 8) | (d & 255);           // src:24b | dst_local:8b
        int q = atomicAdd(&hs[s >> 8], 1);
        bsrc[q] = (unsigned char)(s & 255);
    }
}

// ---------------- per-dst-bucket CSR build: hist + scan + scatter (L1-resident) ----------------
__global__ __launch_bounds__(256) void k_build_csr(const int* __restrict__ cur_d, const int* __restrict__ pairs,
                                                   int* __restrict__ edge_src,
                                                   int* __restrict__ row_beg, int* __restrict__ row_end,
                                                   float* __restrict__ deg_in_inv) {
    __shared__ int h[256];
    __shared__ int base[256];
    __shared__ int sc[256];
    int b = blockIdx.x;
    int p0 = b * BCAP;
    int n = cur_d[b] - p0;
    h[threadIdx.x] = 0;
    __syncthreads();
    for (int i = threadIdx.x; i < n; i += 256)
        atomicAdd(&h[pairs[p0 + i] & 255], 1);
    __syncthreads();
    int v = h[threadIdx.x];
    sc[threadIdx.x] = v;
    __syncthreads();
    #pragma unroll
    for (int off = 1; off < 256; off <<= 1) {
        int t = (threadIdx.x >= off) ? sc[threadIdx.x - off] : 0;
        __syncthreads();
        sc[threadIdx.x] += t;
        __syncthreads();
    }
    int beg = p0 + sc[threadIdx.x] - v;            // exclusive scan, bucket-local CSR (gapped global)
    base[threadIdx.x] = beg;
    int node = b * 256 + (int)threadIdx.x;
    if (node < NN) {
        row_beg[node] = beg;
        row_end[node] = beg + v;
        deg_in_inv[node] = rsqrtf(fmaxf((float)v, 1.0f));
    }
    __syncthreads();
    for (int i = threadIdx.x; i < n; i += 256) {
        int pk = pairs[p0 + i];
        int pos = atomicAdd(&base[pk & 255], 1);
        edge_src[pos] = pk >> 8;
    }
}

// ---------------- per-src-bucket out-degree ----------------
__global__ __launch_bounds__(256) void k_degout(const int* __restrict__ cur_s, const unsigned char* __restrict__ bsrc,
                                                float* __restrict__ deg_out_inv) {
    __shared__ int h[256];
    int b = blockIdx.x;
    int p0 = b * BCAP;
    int n = cur_s[b] - p0;
    h[threadIdx.x] = 0;
    __syncthreads();
    for (int i = threadIdx.x; i < n; i += 256)
        atomicAdd(&h[bsrc[p0 + i]], 1);
    __syncthreads();
    int node = b * 256 + (int)threadIdx.x;
    if (node < NN)
        deg_out_inv[node] = rsqrtf(fmaxf((float)h[threadIdx.x], 1.0f));
}

// ---------------- feat fp32 -> bf16 with deg_out_inv folded ----------------
__global__ __launch_bounds__(256) void k_cvt(const float* __restrict__ feat,
                                             const float* __restrict__ deg_out_inv,
                                             ushort* __restrict__ out) {
    int idx = blockIdx.x * 256 + threadIdx.x;            // one float4 per thread
    if (idx >= NN * 32) return;                          // NN*128/4
    float4 v = *(const float4*)(feat + (size_t)idx * 4);
    float w = deg_out_inv[idx >> 5];                     // (idx*4)/128
    ushort4 o;
    o.x = bf16_rtn(v.x * w);
    o.y = bf16_rtn(v.y * w);
    o.z = bf16_rtn(v.z * w);
    o.w = bf16_rtn(v.w * w);
    *(ushort4*)(out + (size_t)idx * 4) = o;
}

// ---------------- pull aggregation over bf16 rows ----------------
// One wave per dst node; the two 32-lane halves gather DIFFERENT edges' rows,
// 4 gathers in flight (8 edges), clamped indices + 0/1 weights.
template <int D, bool FINAL>
__global__ __launch_bounds__(256) void k_agg(const ushort* __restrict__ x, const int* __restrict__ edge_src,
                                             const int* __restrict__ row_beg,
                                             const int* __restrict__ row_end,
                                             const float* __restrict__ deg_in_inv,
                                             const float* __restrict__ bias,
                                             ushort* __restrict__ out_b,
                                             float* __restrict__ out_f) {
    constexpr int VEC = D / 32;               // cols per lane within a half-wave row
    int node = blockIdx.x * 4 + (threadIdx.x >> 6);
    int lane = threadIdx.x & 63;
    int half = lane >> 5;
    int l5 = lane & 31;
    int beg = row_beg[node];
    int end = row_end[node];
    float acc[VEC];
    #pragma unroll
    for (int v = 0; v < VEC; ++v) acc[v] = 0.0f;
    const ushort* xb = x + (size_t)l5 * VEC;
    for (int i = beg; i < end; i += 8) {
        int id[4];
        float w[4];
        #pragma unroll
        for (int u = 0; u < 4; ++u) {
            int e = i + 2 * u + half;
            id[u] = edge_src[min(e, end - 1)];
            w[u] = (e < end) ? 1.0f : 0.0f;
        }
        #pragma unroll
        for (int u = 0; u < 4; ++u) {
            if constexpr (VEC == 8) {
                ushort8 val = *(const ushort8*)(xb + (size_t)id[u] * D);
                #pragma unroll
                for (int v = 0; v < 8; ++v) acc[v] = fmaf(w[u], bf16_to_f(val[v]), acc[v]);
            } else {
                ushort4 val = *(const ushort4*)(xb + (size_t)id[u] * D);
                acc[0] = fmaf(w[u], bf16_to_f(val.x), acc[0]);
                acc[1] = fmaf(w[u], bf16_to_f(val.y), acc[1]);
                acc[2] = fmaf(w[u], bf16_to_f(val.z), acc[2]);
                acc[3] = fmaf(w[u], bf16_to_f(val.w), acc[3]);
            }
        }
    }
    #pragma unroll
    for (int v = 0; v < VEC; ++v) acc[v] += __shfl_xor(acc[v], 32);
    if (half == 0) {
        if constexpr (FINAL) {
            float dv = deg_in_inv[node];
            float4 bv = *(const float4*)(bias + l5 * 4);
            float4 o4;
            o4.x = (acc[0] + bv.x) * dv;
            o4.y = (acc[1] + bv.y) * dv;
            o4.z = (acc[2] + bv.z) * dv;
            o4.w = (acc[3] + bv.w) * dv;
            *(float4*)(out_f + (size_t)node * D + l5 * 4) = o4;
        } else {
            ushort* o = out_b + (size_t)node * D + l5 * VEC;
            if constexpr (VEC == 8) {
                ushort8 uv;
                #pragma unroll
                for (int v = 0; v < 8; ++v) uv[v] = bf16_rtn(acc[v]);
                *(ushort8*)o = uv;
            } else {
                ushort4 uv;
                uv.x = bf16_rtn(acc[0]); uv.y = bf16_rtn(acc[1]);
                uv.z = bf16_rtn(acc[2]); uv.w = bf16_rtn(acc[3]);
                *(ushort4*)o = uv;
            }
        }
    }
}

// ---------------- pack W[K x M] fp32 -> B-fragment-ordered bf16 hi/lo planes ----------------
template <int K, int M>
__device__ inline void packW_dev(const float* __restrict__ W, ushort* __restrict__ out, int blk) {
    constexpr int NT = M / 16, KC = K / 32;
    constexpr int WTOT = KC * NT * 512;      // elements per plane
    int idx = blk * 256 + (int)threadIdx.x;
    int lane = idx & 63;
    int tile = idx >> 6;
    int nt = tile % NT, kc = tile / NT;
    int col = nt * 16 + (lane & 15);
    int kbase = kc * 32 + (lane >> 4) * 8;
    size_t o = (size_t)tile * 512 + lane * 8;
    #pragma unroll
    for (int j = 0; j < 8; ++j) {
        float w = W[(size_t)(kbase + j) * M + col];
        uint32_t u = __float_as_uint(w);
        uint32_t hu = u & 0xffff0000u;
        float lf = w - __uint_as_float(hu);
        out[o + j] = (ushort)(u >> 16);
        out[o + WTOT + j] = (ushort)(__float_as_uint(lf) >> 16);
    }
}

__global__ __launch_bounds__(256) void k_packAll(const float* __restrict__ W1, ushort* __restrict__ o1,
                                                 const float* __restrict__ W2, ushort* __restrict__ o2,
                                                 const float* __restrict__ W3, ushort* __restrict__ o3) {
    int b = blockIdx.x;
    if (b < 16) packW_dev<128, 256>(W1, o1, b);            // 4*16 tiles
    else if (b < 48) packW_dev<256, 256>(W2, o2, b - 16);  // 8*16 tiles
    else packW_dev<256, 128>(W3, o3, b - 48);              // 8*8 tiles
}

// ---------------- bf16 MFMA GEMM, 64x64 wave tiles, fused epilogue ----------------
// Wave tile: 64 rows x 64 cols (4 row-frags x 4 col-tiles); each B-frag load
// feeds 4 MFMAs, each A-frag load feeds 8 -> 32 MFMAs per 12 loads per kc.
// M=256: block = 64 rows x 256 cols (4 col-wave groups, cross-wave LDS LN).
// M=128: block = 128 rows x 128 cols (2x2 wave grid).
// MODE 0: out = bf16(A@W)
// MODE 1: out = bf16(prelu(LN((A@W+b)*deg_in)) * deg_out)   [requires M=256]
template <int K, int M, int MODE>
__global__ __launch_bounds__(256) void k_gemm_mfma(const ushort* __restrict__ A,
                                                   const ushort* __restrict__ Wp,
                                                   const float* __restrict__ bias,
                                                   const float* __restrict__ deg_in_inv,
                                                   const float* __restrict__ deg_out_inv,
                                                   const float* __restrict__ g,
                                                   const float* __restrict__ be,
                                                   const float* __restrict__ a,
                                                   ushort* __restrict__ out) {
    constexpr int NT = M / 16;
    constexpr int KC = K / 32;
    constexpr int WTOT = KC * NT * 512;
    constexpr int COLW = M / 64;          // waves across cols (4 for M=256, 2 for M=128)
    constexpr int ROWW = 4 / COLW;        // row groups per block
    constexpr int BROWS = 64 * ROWW;      // rows per block
    constexpr int LROW = M + 8;           // padded LDS row (ushorts)
    __shared__ ushort sbuf[BROWS * LROW];
    __shared__ float sredS[4][64];
    __shared__ float sredQ[4][64];
    __shared__ float smu[64];
    __shared__ float srs[64];

    int lane = threadIdx.x & 63;
    int wave = threadIdx.x >> 6;
    int cw = wave % COLW;                 // col group
    int rw = wave / COLW;                 // row group (0 when M=256)
    int m = lane & 15;
    int quad = lane >> 4;
    int rowb = blockIdx.x * BROWS + rw * 64;

    f32x4 acc[4][4];
    #pragma unroll
    for (int rf = 0; rf < 4; ++rf)
        #pragma unroll
        for (int ct = 0; ct < 4; ++ct) acc[rf][ct] = (f32x4){0.f, 0.f, 0.f, 0.f};

    const ushort* abase = A + (size_t)(rowb + m) * K + quad * 8;
    for (int kc = 0; kc < KC; ++kc) {
        short8 av[4];
        #pragma unroll
        for (int rf = 0; rf < 4; ++rf)
            av[rf] = *(const short8*)(abase + (size_t)rf * 16 * K + kc * 32);
        const ushort* wb0 = Wp + ((size_t)kc * NT + cw * 4) * 512 + lane * 8;
        #pragma unroll
        for (int ct = 0; ct < 4; ++ct) {
            short8 bh = *(const short8*)(wb0 + ct * 512);
            short8 bl = *(const short8*)(wb0 + WTOT + ct * 512);
            #pragma unroll
            for (int rf = 0; rf < 4; ++rf) {
                acc[rf][ct] = __builtin_amdgcn_mfma_f32_16x16x32_bf16(av[rf], bh, acc[rf][ct], 0, 0, 0);
                acc[rf][ct] = __builtin_amdgcn_mfma_f32_16x16x32_bf16(av[rf], bl, acc[rf][ct], 0, 0, 0);
            }
        }
    }
    // acc[rf][ct][r] holds row_local = rw*64 + rf*16 + quad*4 + r, col = cw*64 + ct*16 + m
    if constexpr (MODE == 1) {
        // bias + deg_in
        float bia[4];
        #pragma unroll
        for (int ct = 0; ct < 4; ++ct) bia[ct] = bias[cw * 64 + ct * 16 + m];
        float din[4][4], fold[4][4];
        #pragma unroll
        for (int rf = 0; rf < 4; ++rf)
            #pragma unroll
            for (int r = 0; r < 4; ++r) {
                int row = rowb + rf * 16 + quad * 4 + r;
                din[rf][r] = deg_in_inv[row];
                fold[rf][r] = deg_out_inv[row];
            }
        float s[4][4], q[4][4];
        #pragma unroll
        for (int rf = 0; rf < 4; ++rf)
            #pragma unroll
            for (int r = 0; r < 4; ++r) { s[rf][r] = 0.f; q[rf][r] = 0.f; }
        #pragma unroll
        for (int rf = 0; rf < 4; ++rf)
            #pragma unroll
            for (int ct = 0; ct < 4; ++ct)
                #pragma unroll
                for (int r = 0; r < 4; ++r) {
                    float v = (acc[rf][ct][r] + bia[ct]) * din[rf][r];
                    acc[rf][ct][r] = v;
                    s[rf][r] += v;
                    q[rf][r] += v * v;
                }
        // reduce over the 16 m-lanes of this quad -> wave partial for 64 cols
        #pragma unroll
        for (int w = 1; w < 16; w <<= 1)
            #pragma unroll
            for (int rf = 0; rf < 4; ++rf)
                #pragma unroll
                for (int r = 0; r < 4; ++r) {
                    s[rf][r] += __shfl_xor(s[rf][r], w);
                    q[rf][r] += __shfl_xor(q[rf][r], w);
                }
        if (m == 0) {
            #pragma unroll
            for (int rf = 0; rf < 4; ++rf)
                #pragma unroll
                for (int r = 0; r < 4; ++r) {
                    int rl = rf * 16 + quad * 4 + r;
                    sredS[wave][rl] = s[rf][r];
                    sredQ[wave][rl] = q[rf][r];
                }
        }
        __syncthreads();
        if (threadIdx.x < 64) {
            int rl = threadIdx.x;
            float st = sredS[0][rl] + sredS[1][rl] + sredS[2][rl] + sredS[3][rl];
            float qt = sredQ[0][rl] + sredQ[1][rl] + sredQ[2][rl] + sredQ[3][rl];
            float mu = st * (1.0f / M);
            float var = qt * (1.0f / M) - mu * mu;
            smu[rl] = mu;
            srs[rl] = rsqrtf(var + 1e-5f);
        }
        __syncthreads();
        float alpha = a[0];
        float gv[4], bev[4];
        #pragma unroll
        for (int ct = 0; ct < 4; ++ct) {
            gv[ct] = g[cw * 64 + ct * 16 + m];
            bev[ct] = be[cw * 64 + ct * 16 + m];
        }
        #pragma unroll
        for (int rf = 0; rf < 4; ++rf)
            #pragma unroll
            for (int r = 0; r < 4; ++r) {
                int rl = rf * 16 + quad * 4 + r;
                float mu = smu[rl];
                float rs = srs[rl];
                float fo = fold[rf][r];
                #pragma unroll
                for (int ct = 0; ct < 4; ++ct) {
                    float v = gv[ct] * (acc[rf][ct][r] - mu) * rs + bev[ct];
                    v = (v >= 0.0f) ? v : alpha * v;
                    v *= fo;
                    sbuf[rl * LROW + cw * 64 + ct * 16 + m] = bf16_rtn(v);
                }
            }
    } else {
        #pragma unroll
        for (int rf = 0; rf < 4; ++rf)
            #pragma unroll
            for (int ct = 0; ct < 4; ++ct)
                #pragma unroll
                for (int r = 0; r < 4; ++r)
                    sbuf[(rw * 64 + rf * 16 + quad * 4 + r) * LROW + cw * 64 + ct * 16 + m] =
                        bf16_rtn(acc[rf][ct][r]);
    }
    __syncthreads();
    // coalesced bf16 write-back: thread covers 64 contiguous ushorts of one row
    constexpr int CNT = BROWS * M / 256;        // 64 both cases
    int trow = ((int)threadIdx.x * CNT) / M;
    int tcol = ((int)threadIdx.x * CNT) % M;
    const ushort* rsrc = sbuf + trow * LROW + tcol;
    ushort* gdst = out + (size_t)(blockIdx.x * BROWS + trow) * M + tcol;
    #pragma unroll
    for (int j = 0; j < CNT / 8; ++j) {
        ushort8 v = *(const ushort8*)(rsrc + j * 8);
        *(ushort8*)(gdst + j * 8) = v;
    }
}

extern "C" void kernel_launch(void* const* d_in, const int* in_sizes, int n_in,
                              void* d_out, int out_size, void* d_ws, size_t ws_size,
                              hipStream_t stream) {
    const float* feat = (const float*)d_in[0];
    const float* W1 = (const float*)d_in[1];
    const float* b1 = (const float*)d_in[2];
    const float* g1 = (const float*)d_in[3];
    const float* be1 = (const float*)d_in[4];
    const float* a1 = (const float*)d_in[5];
    const float* W2 = (const float*)d_in[6];
    const float* b2 = (const float*)d_in[7];
    const float* g2 = (const float*)d_in[8];
    const float* be2 = (const float*)d_in[9];
    const float* a2 = (const float*)d_in[10];
    const float* W3 = (const float*)d_in[11];
    const float* b3 = (const float*)d_in[12];
    const int* src = (const int*)d_in[13];
    const int* dst = (const int*)d_in[14];

    char* ws = (char*)d_ws;
    size_t off = 0;
    auto alloc = [&](size_t bytes) -> void* {
        off = (off + 511) & ~(size_t)511;
        void* p = ws + off;
        off += bytes;
        return p;
    };
    int* cur_d = (int*)alloc((size_t)NBUCK * 4);
    int* cur_s = (int*)alloc((size_t)NBUCK * 4);
    float* deg_out_inv = (float*)alloc((size_t)NP * 4);
    float* deg_in_inv = (float*)alloc((size_t)NP * 4);
    int* row_beg = (int*)alloc((size_t)NN * 4);
    int* row_end = (int*)alloc((size_t)NN * 4);
    int* pairs = (int*)alloc((size_t)NBUCK * BCAP * 4);
    unsigned char* bsrc = (unsigned char*)alloc((size_t)NBUCK * BCAP);
    int* edge_src = (int*)alloc((size_t)NBUCK * BCAP * 4);
    ushort* Wp1 = (ushort*)alloc((size_t)2 * 4 * 16 * 512 * 2);   // K=128,M=256 hi/lo
    ushort* Wp2 = (ushort*)alloc((size_t)2 * 8 * 16 * 512 * 2);   // K=256,M=256
    ushort* Wp3 = (ushort*)alloc((size_t)2 * 8 * 8 * 512 * 2);    // K=256,M=128
    ushort* featb = (ushort*)alloc((size_t)NP * 128 * 2);   // feat*deg_out, bf16
    ushort* aggb  = (ushort*)alloc((size_t)NP * 256 * 2);   // aggregation output (reused)
    ushort* hb    = (ushort*)alloc((size_t)NP * 256 * 2);   // h*deg_out, bf16 (reused)
    ushort* yb    = (ushort*)alloc((size_t)NP * 128 * 2);   // layer-3 GEMM output
    (void)ws_size; (void)in_sizes; (void)n_in; (void)out_size;

    // graph structure + degrees via two-level bucket partition (no scattered global atomics)
    k_init_cur<<<2, 256, 0, stream>>>(cur_d, cur_s);
    k_partition<<<PBLK, 256, 0, stream>>>(src, dst, cur_d, cur_s, pairs, bsrc);
    k_build_csr<<<NBUCK, 256, 0, stream>>>(cur_d, pairs, edge_src, row_beg, row_end, deg_in_inv);
    k_degout<<<NBUCK, 256, 0, stream>>>(cur_s, bsrc, deg_out_inv);

    // weights -> MFMA fragment order (hi/lo planes); feat -> bf16 with deg_out fold
    k_packAll<<<64, 256, 0, stream>>>(W1, Wp1, W2, Wp2, W3, Wp3);
    k_cvt<<<(NN * 32 + 255) / 256, 256, 0, stream>>>(feat, deg_out_inv, featb);

    // layer 1: agg(feat*deg_out) -> GEMM 128->256 [+b1,*deg_in,LN,PReLU,*deg_out] -> h1b
    k_agg<128, false><<<NN / 4, 256, 0, stream>>>(featb, edge_src, row_beg, row_end, nullptr, nullptr, aggb, nullptr);
    k_gemm_mfma<128, 256, 1><<<NP / 64, 256, 0, stream>>>(aggb, Wp1, b1, deg_in_inv, deg_out_inv, g1, be1, a1, hb);

    // layer 2: agg(h1*deg_out) -> GEMM 256->256 [epilogue] -> h2b (h2*deg_out)
    k_agg<256, false><<<NN / 4, 256, 0, stream>>>(hb, edge_src, row_beg, row_end, nullptr, nullptr, aggb, nullptr);
    k_gemm_mfma<256, 256, 1><<<NP / 64, 256, 0, stream>>>(aggb, Wp2, b2, deg_in_inv, deg_out_inv, g2, be2, a2, hb);

    // layer 3: GEMM (h2*deg_out)@W3 -> yb, then agg(yb) with (+b3)*deg_in into d_out
    k_gemm_mfma<256, 128, 0><<<NP / 128, 256, 0, stream>>>(hb, Wp3, nullptr, nullptr, nullptr, nullptr, nullptr, nullptr, yb);
    k_agg<128, true><<<NN / 4, 256, 0, stream>>>(yb, edge_src, row_beg, row_end, deg_in_inv, b3, nullptr, (float*)d_out);
}